// Round 1
// baseline (542.694 us; speedup 1.0000x reference)
//
#include <hip/hip_runtime.h>

typedef short short8  __attribute__((ext_vector_type(8)));
typedef short short4v __attribute__((ext_vector_type(4)));
typedef float f32x4   __attribute__((ext_vector_type(4)));

#define MFMA_BF16(A,B,C) __builtin_amdgcn_mfma_f32_16x16x32_bf16((A),(B),(C),0,0,0)

__device__ __forceinline__ short bf16bits(float f){
  return (short)__builtin_bit_cast(unsigned short, static_cast<__bf16>(f));
}

// ---------------- fused preprocessing ----------------
// blocks [0,220): mask preprocessing  (region_masks -> allowed bits)
// blocks [220,988): K/V repack to bf16 (Kb row-major, VT transposed)
__global__ __launch_bounds__(256) void prep_kernel(const float* __restrict__ rm,
                                                   const float* __restrict__ k,
                                                   const float* __restrict__ v,
                                                   const float* __restrict__ rk,
                                                   const float* __restrict__ rv,
                                                   unsigned* __restrict__ allowed,
                                                   unsigned short* __restrict__ Kb,
                                                   unsigned short* __restrict__ VT){
  const int bid = blockIdx.x;
  if (bid < 220){
    int s = bid*256 + threadIdx.x;
    if (s >= 56320) return;
    int t = s / 3520;
    int rem = s - t*3520;
    int i = rem / 80;
    int j = rem - i*80;
    int y = 2*i, x = 2*j;
    bool bin[2];
    #pragma unroll
    for (int r=0;r<2;r++){
      const float* base = rm + (size_t)r*121*88*160;
      float acc;
      if (t == 0){
        const float* p0 = base + (size_t)(0*88 + y)*160 + x;
        acc = 0.25f*(p0[0]+p0[1]+p0[160]+p0[161]);
      } else {
        const float* pa = base + (size_t)((8*t-4)*88 + y)*160 + x;
        const float* pb = base + (size_t)((8*t-3)*88 + y)*160 + x;
        acc = 0.125f*(pa[0]+pa[1]+pa[160]+pa[161] + pb[0]+pb[1]+pb[160]+pb[161]);
      }
      bin[r] = acc > 0.5f;
    }
    unsigned bits = (bin[0]||bin[1]) ? 0u : 1u;
    if (bin[0]) bits |= 2u;
    if (bin[1]) bits |= 4u;
    allowed[s] = bits;
  } else {
    int idx = (bid-220)*256 + threadIdx.x;   // over 3*128*8*64 = 196608
    if (idx >= 3*128*8*64) return;
    int d   = idx & 63;
    int h   = (idx >> 6) & 7;
    int p   = (idx >> 9) & 127;
    int seg = idx >> 16;
    int low = idx & 65535;                   // (p*8+h)*64+d
    float kv_, vv_;
    if (seg == 0){ kv_ = k[low];                          vv_ = v[low]; }
    else         { kv_ = rk[(size_t)(seg-1)*65536 + low]; vv_ = rv[(size_t)(seg-1)*65536 + low]; }
    Kb[((h*3 + seg)*128 + p)*64 + d] = (unsigned short)bf16bits(kv_);
    VT[(h*64 + d)*384 + seg*128 + p] = (unsigned short)bf16bits(vv_);
  }
}

// ---------------- fused regional+base attention ----------------
// Single-pass softmax with FIXED reference point (exp(s-8); softmax is
// shift-invariant, so exact): per key-tile -> MFMA -> exp -> accumulate
// partial row sums -> write UNNORMALIZED bf16 e to wave-private LDS.
// Normalization is applied after PV via two accumulators:
//   acc0 = sum_{k<128}  e_raw    * V   (serves base pass AND seg0 of regional)
//   acc1 = sum_{k>=128} e_masked * V
//   out  = (0.5/lbase + bit0*0.5/lreg)*acc0 + (0.5/lreg)*acc1,
//   lreg = bit0*lbase + lrest.
// No __syncthreads (P^T is wave-private); P^T processed in two key-halves
// so LDS = 4*16*200*2 = 25600 B (>=4 blocks/CU with the VGPR cap below).
__global__ __launch_bounds__(256, 4) void attn_kernel(const float* __restrict__ q,
                                                      const unsigned* __restrict__ allowed,
                                                      const unsigned short* __restrict__ Kb,
                                                      const unsigned short* __restrict__ VT,
                                                      float* __restrict__ out){
  constexpr int H = 8, D = 64;
  const int h    = blockIdx.y;
  const int wave = threadIdx.x >> 6;
  const int lane = threadIdx.x & 63;
  const int c    = lane & 15;        // query col
  const int Q    = lane >> 4;        // quad
  const int s0   = blockIdx.x*64 + wave*16;
  const int s    = s0 + c;

  // per-wave half-P^T buffer: [16 queries][200 shorts] (192 keys + pad)
  __shared__ __align__(16) unsigned short pt[4*16*200];
  unsigned short* myrow = pt + wave*(16*200) + c*200;

  // ---- Q fragments (B-operand of S^T): lane: d = Q*8+j (+32 for second frag)
  const float* qp = q + ((size_t)s*H + h)*D + Q*8;
  f32x4 qa  = *(const f32x4*)(qp);
  f32x4 qb  = *(const f32x4*)(qp + 4);
  f32x4 qc_ = *(const f32x4*)(qp + 32);
  f32x4 qd  = *(const f32x4*)(qp + 36);
  short8 qf0, qf1;
  #pragma unroll
  for (int jj=0;jj<4;jj++){
    qf0[jj]   = bf16bits(qa[jj]);
    qf0[4+jj] = bf16bits(qb[jj]);
    qf1[jj]   = bf16bits(qc_[jj]);
    qf1[4+jj] = bf16bits(qd[jj]);
  }

  const unsigned ab = allowed[s];
  const float am1 = (ab >> 1) & 1u ? 1.f : 0.f;   // region 0 (tiles 8..15)
  const float am2 = (ab >> 2) & 1u ? 1.f : 0.f;   // region 1 (tiles 16..23)
  const unsigned short* kbase = Kb + (size_t)h*3*128*64;
  const unsigned short* vb    = VT + (size_t)h*64*384;

  float lbase = 0.f, lrest = 0.f;
  f32x4 acc0[4], acc1[4];
  #pragma unroll
  for (int m=0;m<4;m++){ acc0[m] = (f32x4){0.f,0.f,0.f,0.f}; acc1[m] = (f32x4){0.f,0.f,0.f,0.f}; }

  #pragma unroll
  for (int half=0; half<2; ++half){
    // ---- scores for 12 tiles -> unnormalized exp -> LDS (wave-private)
    #pragma unroll
    for (int tl=0; tl<12; ++tl){
      const int t = half*12 + tl;
      const unsigned short* kp = kbase + (t*16 + c)*64 + Q*8;
      short8 kf0 = *(const short8*)(kp);
      short8 kf1 = *(const short8*)(kp + 32);
      f32x4 sacc = {0.f,0.f,0.f,0.f};
      sacc = MFMA_BF16(kf0, qf0, sacc);
      sacc = MFMA_BF16(kf1, qf1, sacc);
      short4v pk;
      if (t < 8){
        #pragma unroll
        for (int r=0;r<4;r++){
          float e = __expf(sacc[r]*0.125f - 8.f);
          lbase += e;
          pk[r] = bf16bits(e);
        }
      } else {
        const float am = (t < 16) ? am1 : am2;
        #pragma unroll
        for (int r=0;r<4;r++){
          float e = am * __expf(sacc[r]*0.125f - 8.f);
          lrest += e;
          pk[r] = bf16bits(e);
        }
      }
      *(short4v*)(myrow + tl*16 + Q*4) = pk;       // keys t*16+Q*4..+3 of query c
    }
    // ---- PV over this half's 6 key-chunks (same-wave LDS RAW: compiler-ordered)
    #pragma unroll
    for (int kl=0; kl<6; ++kl){
      const int kc = half*6 + kl;
      short8 pf = *(const short8*)(myrow + kl*32 + Q*8);
      #pragma unroll
      for (int m=0;m<4;m++){
        short8 vf = *(const short8*)(vb + (m*16 + c)*384 + kc*32 + Q*8);
        if (kc < 4) acc0[m] = MFMA_BF16(vf, pf, acc0[m]);
        else        acc1[m] = MFMA_BF16(vf, pf, acc1[m]);
      }
    }
  }

  // ---- row-sum reductions (queries live in lane&15; reduce across quads)
  lbase += __shfl_xor(lbase, 16); lbase += __shfl_xor(lbase, 32);
  lrest += __shfl_xor(lrest, 16); lrest += __shfl_xor(lrest, 32);
  const float invb = 0.5f/lbase;
  const float lreg = ((ab & 1u) ? lbase : 0.f) + lrest;
  const float invr = 0.5f/lreg;
  const float cA = invb + ((ab & 1u) ? invr : 0.f);
  const float cR = invr;

  // ---- store: lane holds d = m*16 + Q*4 + r for query s (fp32, 16B stores)
  float* ob = out + (size_t)s*512 + h*64 + Q*4;
  #pragma unroll
  for (int m=0;m<4;m++){
    f32x4 o;
    #pragma unroll
    for (int r=0;r<4;r++) o[r] = acc0[m][r]*cA + acc1[m][r]*cR;
    *(f32x4*)(ob + m*16) = o;
  }
}

extern "C" void kernel_launch(void* const* d_in, const int* in_sizes, int n_in,
                              void* d_out, int out_size, void* d_ws, size_t ws_size,
                              hipStream_t stream) {
  const float* q  = (const float*)d_in[0];
  const float* k  = (const float*)d_in[1];
  const float* v  = (const float*)d_in[2];
  const float* rk = (const float*)d_in[3];
  const float* rv = (const float*)d_in[4];
  const float* rm = (const float*)d_in[5];
  float* out = (float*)d_out;

  char* ws = (char*)d_ws;
  unsigned*       allowed = (unsigned*)ws;                           // 56320*4   = 225280 B
  unsigned short* Kb      = (unsigned short*)(ws + 225280);          // 8*3*128*64*2 = 393216 B
  unsigned short* VT      = (unsigned short*)(ws + 225280 + 393216); // 393216 B

  prep_kernel<<<988, 256, 0, stream>>>(rm, k, v, rk, rv, allowed, Kb, VT);
  dim3 grid(880, 8);
  attn_kernel<<<grid, 256, 0, stream>>>(q, allowed, Kb, VT, out);
}

// Round 2
// 491.538 us; speedup vs baseline: 1.1041x; 1.1041x over previous
//
#include <hip/hip_runtime.h>

typedef short short8  __attribute__((ext_vector_type(8)));
typedef short short4v __attribute__((ext_vector_type(4)));
typedef float f32x4   __attribute__((ext_vector_type(4)));

#define MFMA_BF16(A,B,C) __builtin_amdgcn_mfma_f32_16x16x32_bf16((A),(B),(C),0,0,0)

__device__ __forceinline__ short bf16bits(float f){
  return (short)__builtin_bit_cast(unsigned short, static_cast<__bf16>(f));
}

// ---------------- fused preprocessing ----------------
// blocks [0,220): mask preprocessing  (region_masks -> allowed bits)
// blocks [220,988): K/V repack to bf16 (Kb row-major, VT transposed)
__global__ __launch_bounds__(256) void prep_kernel(const float* __restrict__ rm,
                                                   const float* __restrict__ k,
                                                   const float* __restrict__ v,
                                                   const float* __restrict__ rk,
                                                   const float* __restrict__ rv,
                                                   unsigned* __restrict__ allowed,
                                                   unsigned short* __restrict__ Kb,
                                                   unsigned short* __restrict__ VT){
  const int bid = blockIdx.x;
  if (bid < 220){
    int s = bid*256 + threadIdx.x;
    if (s >= 56320) return;
    int t = s / 3520;
    int rem = s - t*3520;
    int i = rem / 80;
    int j = rem - i*80;
    int y = 2*i, x = 2*j;
    bool bin[2];
    #pragma unroll
    for (int r=0;r<2;r++){
      const float* base = rm + (size_t)r*121*88*160;
      float acc;
      if (t == 0){
        const float* p0 = base + (size_t)(0*88 + y)*160 + x;
        acc = 0.25f*(p0[0]+p0[1]+p0[160]+p0[161]);
      } else {
        const float* pa = base + (size_t)((8*t-4)*88 + y)*160 + x;
        const float* pb = base + (size_t)((8*t-3)*88 + y)*160 + x;
        acc = 0.125f*(pa[0]+pa[1]+pa[160]+pa[161] + pb[0]+pb[1]+pb[160]+pb[161]);
      }
      bin[r] = acc > 0.5f;
    }
    unsigned bits = (bin[0]||bin[1]) ? 0u : 1u;
    if (bin[0]) bits |= 2u;
    if (bin[1]) bits |= 4u;
    allowed[s] = bits;
  } else {
    int idx = (bid-220)*256 + threadIdx.x;   // over 3*128*8*64 = 196608
    if (idx >= 3*128*8*64) return;
    int d   = idx & 63;
    int h   = (idx >> 6) & 7;
    int p   = (idx >> 9) & 127;
    int seg = idx >> 16;
    int low = idx & 65535;                   // (p*8+h)*64+d
    float kv_, vv_;
    if (seg == 0){ kv_ = k[low];                          vv_ = v[low]; }
    else         { kv_ = rk[(size_t)(seg-1)*65536 + low]; vv_ = rv[(size_t)(seg-1)*65536 + low]; }
    Kb[((h*3 + seg)*128 + p)*64 + d] = (unsigned short)bf16bits(kv_);
    VT[(h*64 + d)*384 + seg*128 + p] = (unsigned short)bf16bits(vv_);
  }
}

// ---------------- fused regional+base attention ----------------
// Single-pass softmax with FIXED reference point (exp(s-8); softmax is
// shift-invariant, so exact): per key-tile -> MFMA -> exp -> accumulate
// partial row sums -> write UNNORMALIZED bf16 e to wave-private LDS.
// Normalization is applied after PV via two accumulators:
//   acc0 = sum_{k<128}  e_raw    * V   (serves base pass AND seg0 of regional)
//   acc1 = sum_{k>=128} e_masked * V
//   out  = (0.5/lbase + bit0*0.5/lreg)*acc0 + (0.5/lreg)*acc1,
//   lreg = bit0*lbase + lrest.
// No __syncthreads (P^T is wave-private); LDS = 4*16*200*2 = 25600 B.
// NOTE: plain __launch_bounds__(256) — round 1's (256,4) capped VGPR at 64
// and spilled the accumulators to scratch (+230 MB WRITE_SIZE). Let the
// allocator take ~100-120 VGPR (4 waves/SIMD, no spill) like round 0.
__global__ __launch_bounds__(256) void attn_kernel(const float* __restrict__ q,
                                                   const unsigned* __restrict__ allowed,
                                                   const unsigned short* __restrict__ Kb,
                                                   const unsigned short* __restrict__ VT,
                                                   float* __restrict__ out){
  constexpr int H = 8, D = 64;
  const int h    = blockIdx.y;
  const int wave = threadIdx.x >> 6;
  const int lane = threadIdx.x & 63;
  const int c    = lane & 15;        // query col
  const int Q    = lane >> 4;        // quad
  const int s0   = blockIdx.x*64 + wave*16;
  const int s    = s0 + c;

  // per-wave half-P^T buffer: [16 queries][200 shorts] (192 keys + pad)
  __shared__ __align__(16) unsigned short pt[4*16*200];
  unsigned short* myrow = pt + wave*(16*200) + c*200;

  // ---- Q fragments (B-operand of S^T): lane: d = Q*8+j (+32 for second frag)
  const float* qp = q + ((size_t)s*H + h)*D + Q*8;
  f32x4 qa  = *(const f32x4*)(qp);
  f32x4 qb  = *(const f32x4*)(qp + 4);
  f32x4 qc_ = *(const f32x4*)(qp + 32);
  f32x4 qd  = *(const f32x4*)(qp + 36);
  short8 qf0, qf1;
  #pragma unroll
  for (int jj=0;jj<4;jj++){
    qf0[jj]   = bf16bits(qa[jj]);
    qf0[4+jj] = bf16bits(qb[jj]);
    qf1[jj]   = bf16bits(qc_[jj]);
    qf1[4+jj] = bf16bits(qd[jj]);
  }

  const unsigned ab = allowed[s];
  const float am1 = (ab >> 1) & 1u ? 1.f : 0.f;   // region 0 (tiles 8..15)
  const float am2 = (ab >> 2) & 1u ? 1.f : 0.f;   // region 1 (tiles 16..23)
  const unsigned short* kbase = Kb + (size_t)h*3*128*64;
  const unsigned short* vb    = VT + (size_t)h*64*384;

  float lbase = 0.f, lrest = 0.f;
  f32x4 acc0[4], acc1[4];
  #pragma unroll
  for (int m=0;m<4;m++){ acc0[m] = (f32x4){0.f,0.f,0.f,0.f}; acc1[m] = (f32x4){0.f,0.f,0.f,0.f}; }

  #pragma unroll
  for (int half=0; half<2; ++half){
    // ---- scores for 12 tiles -> unnormalized exp -> LDS (wave-private)
    #pragma unroll
    for (int tl=0; tl<12; ++tl){
      const int t = half*12 + tl;
      const unsigned short* kp = kbase + (t*16 + c)*64 + Q*8;
      short8 kf0 = *(const short8*)(kp);
      short8 kf1 = *(const short8*)(kp + 32);
      f32x4 sacc = {0.f,0.f,0.f,0.f};
      sacc = MFMA_BF16(kf0, qf0, sacc);
      sacc = MFMA_BF16(kf1, qf1, sacc);
      short4v pk;
      if (t < 8){
        #pragma unroll
        for (int r=0;r<4;r++){
          float e = __expf(sacc[r]*0.125f - 8.f);
          lbase += e;
          pk[r] = bf16bits(e);
        }
      } else {
        const float am = (t < 16) ? am1 : am2;
        #pragma unroll
        for (int r=0;r<4;r++){
          float e = am * __expf(sacc[r]*0.125f - 8.f);
          lrest += e;
          pk[r] = bf16bits(e);
        }
      }
      *(short4v*)(myrow + tl*16 + Q*4) = pk;       // keys t*16+Q*4..+3 of query c
    }
    // ---- PV over this half's 6 key-chunks (same-wave LDS RAW: compiler-ordered)
    #pragma unroll
    for (int kl=0; kl<6; ++kl){
      const int kc = half*6 + kl;
      short8 pf = *(const short8*)(myrow + kl*32 + Q*8);
      #pragma unroll
      for (int m=0;m<4;m++){
        short8 vf = *(const short8*)(vb + (m*16 + c)*384 + kc*32 + Q*8);
        if (kc < 4) acc0[m] = MFMA_BF16(vf, pf, acc0[m]);
        else        acc1[m] = MFMA_BF16(vf, pf, acc1[m]);
      }
    }
  }

  // ---- row-sum reductions (queries live in lane&15; reduce across quads)
  lbase += __shfl_xor(lbase, 16); lbase += __shfl_xor(lbase, 32);
  lrest += __shfl_xor(lrest, 16); lrest += __shfl_xor(lrest, 32);
  const float invb = 0.5f/lbase;
  const float lreg = ((ab & 1u) ? lbase : 0.f) + lrest;
  const float invr = 0.5f/lreg;
  const float cA = invb + ((ab & 1u) ? invr : 0.f);
  const float cR = invr;

  // ---- store: lane holds d = m*16 + Q*4 + r for query s (fp32, 16B stores)
  float* ob = out + (size_t)s*512 + h*64 + Q*4;
  #pragma unroll
  for (int m=0;m<4;m++){
    f32x4 o;
    #pragma unroll
    for (int r=0;r<4;r++) o[r] = acc0[m][r]*cA + acc1[m][r]*cR;
    *(f32x4*)(ob + m*16) = o;
  }
}

extern "C" void kernel_launch(void* const* d_in, const int* in_sizes, int n_in,
                              void* d_out, int out_size, void* d_ws, size_t ws_size,
                              hipStream_t stream) {
  const float* q  = (const float*)d_in[0];
  const float* k  = (const float*)d_in[1];
  const float* v  = (const float*)d_in[2];
  const float* rk = (const float*)d_in[3];
  const float* rv = (const float*)d_in[4];
  const float* rm = (const float*)d_in[5];
  float* out = (float*)d_out;

  char* ws = (char*)d_ws;
  unsigned*       allowed = (unsigned*)ws;                           // 56320*4   = 225280 B
  unsigned short* Kb      = (unsigned short*)(ws + 225280);          // 8*3*128*64*2 = 393216 B
  unsigned short* VT      = (unsigned short*)(ws + 225280 + 393216); // 393216 B

  prep_kernel<<<988, 256, 0, stream>>>(rm, k, v, rk, rv, allowed, Kb, VT);
  dim3 grid(880, 8);
  attn_kernel<<<grid, 256, 0, stream>>>(q, allowed, Kb, VT, out);
}

// Round 3
// 346.947 us; speedup vs baseline: 1.5642x; 1.4168x over previous
//
#include <hip/hip_runtime.h>

typedef short short8  __attribute__((ext_vector_type(8)));
typedef short short4v __attribute__((ext_vector_type(4)));
typedef float f32x4   __attribute__((ext_vector_type(4)));

#define MFMA_BF16(A,B,C) __builtin_amdgcn_mfma_f32_16x16x32_bf16((A),(B),(C),0,0,0)

__device__ __forceinline__ short bf16bits(float f){
  return (short)__builtin_bit_cast(unsigned short, static_cast<__bf16>(f));
}

// ---------------- fused preprocessing ----------------
// blocks [0,220): mask preprocessing  (region_masks -> allowed bits)
// blocks [220,988): K/V repack to bf16 (Kb row-major, VT transposed)
__global__ __launch_bounds__(256) void prep_kernel(const float* __restrict__ rm,
                                                   const float* __restrict__ k,
                                                   const float* __restrict__ v,
                                                   const float* __restrict__ rk,
                                                   const float* __restrict__ rv,
                                                   unsigned* __restrict__ allowed,
                                                   unsigned short* __restrict__ Kb,
                                                   unsigned short* __restrict__ VT){
  const int bid = blockIdx.x;
  if (bid < 220){
    int s = bid*256 + threadIdx.x;
    if (s >= 56320) return;
    int t = s / 3520;
    int rem = s - t*3520;
    int i = rem / 80;
    int j = rem - i*80;
    int y = 2*i, x = 2*j;
    bool bin[2];
    #pragma unroll
    for (int r=0;r<2;r++){
      const float* base = rm + (size_t)r*121*88*160;
      float acc;
      if (t == 0){
        const float* p0 = base + (size_t)(0*88 + y)*160 + x;
        acc = 0.25f*(p0[0]+p0[1]+p0[160]+p0[161]);
      } else {
        const float* pa = base + (size_t)((8*t-4)*88 + y)*160 + x;
        const float* pb = base + (size_t)((8*t-3)*88 + y)*160 + x;
        acc = 0.125f*(pa[0]+pa[1]+pa[160]+pa[161] + pb[0]+pb[1]+pb[160]+pb[161]);
      }
      bin[r] = acc > 0.5f;
    }
    unsigned bits = (bin[0]||bin[1]) ? 0u : 1u;
    if (bin[0]) bits |= 2u;
    if (bin[1]) bits |= 4u;
    allowed[s] = bits;
  } else {
    int idx = (bid-220)*256 + threadIdx.x;   // over 3*128*8*64 = 196608
    if (idx >= 3*128*8*64) return;
    int d   = idx & 63;
    int h   = (idx >> 6) & 7;
    int p   = (idx >> 9) & 127;
    int seg = idx >> 16;
    int low = idx & 65535;                   // (p*8+h)*64+d
    float kv_, vv_;
    if (seg == 0){ kv_ = k[low];                          vv_ = v[low]; }
    else         { kv_ = rk[(size_t)(seg-1)*65536 + low]; vv_ = rv[(size_t)(seg-1)*65536 + low]; }
    Kb[((h*3 + seg)*128 + p)*64 + d] = (unsigned short)bf16bits(kv_);
    VT[(h*64 + d)*384 + seg*128 + p] = (unsigned short)bf16bits(vv_);
  }
}

// ---------------- fused regional+base attention, LDS-staged ----------------
// 512 threads (8 waves) per (head, 256-query chunk). Stage full head K (48KB,
// rows of 128B) and V^T (48KB, rows of 768B) into LDS ONCE with XOR swizzle
// (phys = linear ^ ((row&7)<<4), rows are 0 mod 128B -> 8-way conflict
// otherwise; swizzle applied identically on write and read, rule both-sides).
// Each wave owns 32 queries (two 16-col sets A/B sharing every K/V fragment).
// 6 phases of {4 score tiles -> unnormalized exp(s-8) -> P^T LDS (4KB/wave,
// 64-key rows of 128B, same swizzle); 2 PV chunks}. Single __syncthreads
// after staging; P^T is wave-private. LDS total = 48+48+32 = 128KB.
__global__ __launch_bounds__(512) void attn_kernel(const float* __restrict__ q,
                                                   const unsigned* __restrict__ allowed,
                                                   const unsigned short* __restrict__ Kb,
                                                   const unsigned short* __restrict__ VT,
                                                   float* __restrict__ out){
  const int h    = blockIdx.y;
  const int wave = threadIdx.x >> 6;
  const int lane = threadIdx.x & 63;
  const int c    = lane & 15;        // query col within set / row-index base
  const int Q    = lane >> 4;        // quad

  __shared__ __align__(16) char Ks[49152];   // 384 key-rows x 128B
  __shared__ __align__(16) char Vs[49152];   // 64 d-rows x 768B
  __shared__ __align__(16) char Ps[32768];   // 8 waves x 32 q-rows x 128B

  const int sA = blockIdx.x*256 + wave*32 + c;
  const int sB = sA + 16;

  // ---- early global loads (overlap with staging)
  const unsigned abA = allowed[sA], abB = allowed[sB];
  const float* qpA = q + ((size_t)sA*8 + h)*64 + Q*8;
  const float* qpB = q + ((size_t)sB*8 + h)*64 + Q*8;
  f32x4 qA0 = *(const f32x4*)(qpA);
  f32x4 qA1 = *(const f32x4*)(qpA+4);
  f32x4 qA2 = *(const f32x4*)(qpA+32);
  f32x4 qA3 = *(const f32x4*)(qpA+36);
  f32x4 qB0 = *(const f32x4*)(qpB);
  f32x4 qB1 = *(const f32x4*)(qpB+4);
  f32x4 qB2 = *(const f32x4*)(qpB+32);
  f32x4 qB3 = *(const f32x4*)(qpB+36);

  // ---- stage K and V^T: each wave 6KB of each, 16B/lane coalesced reads,
  //      swizzled ds_writes (consecutive 8 lanes -> 8 distinct 16B slots)
  {
    const char* kg = (const char*)(Kb + (size_t)h*24576);  // 48KB per head
    const char* vg = (const char*)(VT + (size_t)h*24576);  // 48KB per head
    #pragma unroll
    for (int i=0;i<6;i++){
      const int off = wave*6144 + i*1024 + lane*16;
      short8 kval = *(const short8*)(kg + off);
      short8 vval = *(const short8*)(vg + off);
      const int krow = off >> 7;     // K row = 128B
      const int vrow = off / 768;    // V^T row = 768B (row*768 is 0 mod 256)
      *(short8*)(Ks + (off ^ ((krow&7)<<4))) = kval;
      *(short8*)(Vs + (off ^ ((vrow&7)<<4))) = vval;
    }
  }

  // ---- bf16 Q fragments (B-operand): lane holds q[s(c)][d=Q*8+j (+32)]
  short8 fA0, fA1, fB0, fB1;
  #pragma unroll
  for (int j=0;j<4;j++){
    fA0[j] = bf16bits(qA0[j]); fA0[4+j] = bf16bits(qA1[j]);
    fA1[j] = bf16bits(qA2[j]); fA1[4+j] = bf16bits(qA3[j]);
    fB0[j] = bf16bits(qB0[j]); fB0[4+j] = bf16bits(qB1[j]);
    fB1[j] = bf16bits(qB2[j]); fB1[4+j] = bf16bits(qB3[j]);
  }

  __syncthreads();   // staged K/V visible to all waves

  // ---- per-lane swizzled base offsets
  const int sx   = (c&7)<<4;         // XOR key, bits 4-6
  const int sx40 = sx & 0x40;
  const int sx60 = sx & 0x60;
  const int kb0  = c*128 + ((Q*16)      ^ sx);              // K frag lo
  const int kb1  = c*128 + ((Q*16 + 64) ^ sx);              // K frag hi
  const int pwb  = wave*4096 + c*128 + ((Q*8)  ^ (sx & 0x10)); // P write base
  const int prA  = wave*4096 + c*128 + ((Q*16) ^ (sx & 0x30)); // P read base (set A)
  const int vrb  = c*768 + ((Q*16) ^ (sx & 0x30));          // V^T read base

  const float amA1 = (abA>>1)&1u ? 1.f : 0.f;
  const float amA2 = (abA>>2)&1u ? 1.f : 0.f;
  const float amB1 = (abB>>1)&1u ? 1.f : 0.f;
  const float amB2 = (abB>>2)&1u ? 1.f : 0.f;

  float lbA=0.f, lrA=0.f, lbB=0.f, lrB=0.f;
  f32x4 aA0[4], aA1[4], aB0[4], aB1[4];
  #pragma unroll
  for (int m=0;m<4;m++){
    aA0[m]=(f32x4){0,0,0,0}; aA1[m]=(f32x4){0,0,0,0};
    aB0[m]=(f32x4){0,0,0,0}; aB1[m]=(f32x4){0,0,0,0};
  }

  #pragma unroll
  for (int ph=0; ph<6; ++ph){
    // ---- 4 score tiles (64 keys) -> unnormalized exp(s-8) -> P^T LDS
    #pragma unroll
    for (int i=0;i<4;i++){
      const int t = ph*4 + i;
      short8 kf0 = *(const short8*)(Ks + kb0 + t*2048);
      short8 kf1 = *(const short8*)(Ks + kb1 + t*2048);
      f32x4 s4A = {0,0,0,0}; s4A = MFMA_BF16(kf0,fA0,s4A); s4A = MFMA_BF16(kf1,fA1,s4A);
      f32x4 s4B = {0,0,0,0}; s4B = MFMA_BF16(kf0,fB0,s4B); s4B = MFMA_BF16(kf1,fB1,s4B);
      short4v pA, pB;
      if (ph < 2){
        #pragma unroll
        for (int r=0;r<4;r++){
          float eA = __expf(s4A[r]*0.125f - 8.f); lbA += eA; pA[r] = bf16bits(eA);
          float eB = __expf(s4B[r]*0.125f - 8.f); lbB += eB; pB[r] = bf16bits(eB);
        }
      } else {
        const float aAm = (ph<4)? amA1 : amA2;
        const float aBm = (ph<4)? amB1 : amB2;
        #pragma unroll
        for (int r=0;r<4;r++){
          float eA = aAm*__expf(s4A[r]*0.125f - 8.f); lrA += eA; pA[r] = bf16bits(eA);
          float eB = aBm*__expf(s4B[r]*0.125f - 8.f); lrB += eB; pB[r] = bf16bits(eB);
        }
      }
      const int wo = (i*32) ^ sx60;  // tile offset xor swizzle hi-bits
      *(short4v*)(Ps + pwb + wo)        = pA;  // set A rows (0-15)
      *(short4v*)(Ps + pwb + 2048 + wo) = pB;  // set B rows (16-31)
    }
    // ---- 2 PV chunks (32 keys each); V frag shared by both query sets
    #pragma unroll
    for (int klp=0; klp<2; ++klp){
      const int kc = ph*2 + klp;
      const int po = (klp*64) ^ sx40;
      short8 pfA = *(const short8*)(Ps + prA + po);
      short8 pfB = *(const short8*)(Ps + prA + 2048 + po);
      const int vo = (kc*64) ^ sx40;
      #pragma unroll
      for (int m=0;m<4;m++){
        short8 vf = *(const short8*)(Vs + vrb + vo + m*12288);
        if (ph<2){ aA0[m] = MFMA_BF16(vf,pfA,aA0[m]); aB0[m] = MFMA_BF16(vf,pfB,aB0[m]); }
        else     { aA1[m] = MFMA_BF16(vf,pfA,aA1[m]); aB1[m] = MFMA_BF16(vf,pfB,aB1[m]); }
      }
    }
  }

  // ---- row-sum reductions (query lives in lane&15; reduce across quads)
  lbA += __shfl_xor(lbA,16); lbA += __shfl_xor(lbA,32);
  lrA += __shfl_xor(lrA,16); lrA += __shfl_xor(lrA,32);
  lbB += __shfl_xor(lbB,16); lbB += __shfl_xor(lbB,32);
  lrB += __shfl_xor(lrB,16); lrB += __shfl_xor(lrB,32);

  const float invbA = 0.5f/lbA;
  const float lregA = ((abA&1u)? lbA : 0.f) + lrA;
  const float invrA = 0.5f/lregA;
  const float cA_A  = invbA + ((abA&1u)? invrA : 0.f);

  const float invbB = 0.5f/lbB;
  const float lregB = ((abB&1u)? lbB : 0.f) + lrB;
  const float invrB = 0.5f/lregB;
  const float cA_B  = invbB + ((abB&1u)? invrB : 0.f);

  // ---- store: lane holds d = m*16 + Q*4 + r for its query (fp32, 16B)
  float* obA = out + (size_t)sA*512 + h*64 + Q*4;
  float* obB = out + (size_t)sB*512 + h*64 + Q*4;
  #pragma unroll
  for (int m=0;m<4;m++){
    f32x4 oA, oB;
    #pragma unroll
    for (int r=0;r<4;r++){
      oA[r] = aA0[m][r]*cA_A + aA1[m][r]*invrA;
      oB[r] = aB0[m][r]*cA_B + aB1[m][r]*invrB;
    }
    *(f32x4*)(obA + m*16) = oA;
    *(f32x4*)(obB + m*16) = oB;
  }
}

extern "C" void kernel_launch(void* const* d_in, const int* in_sizes, int n_in,
                              void* d_out, int out_size, void* d_ws, size_t ws_size,
                              hipStream_t stream) {
  const float* q  = (const float*)d_in[0];
  const float* k  = (const float*)d_in[1];
  const float* v  = (const float*)d_in[2];
  const float* rk = (const float*)d_in[3];
  const float* rv = (const float*)d_in[4];
  const float* rm = (const float*)d_in[5];
  float* out = (float*)d_out;

  char* ws = (char*)d_ws;
  unsigned*       allowed = (unsigned*)ws;                           // 56320*4   = 225280 B
  unsigned short* Kb      = (unsigned short*)(ws + 225280);          // 8*3*128*64*2 = 393216 B
  unsigned short* VT      = (unsigned short*)(ws + 225280 + 393216); // 393216 B

  prep_kernel<<<988, 256, 0, stream>>>(rm, k, v, rk, rv, allowed, Kb, VT);
  dim3 grid(220, 8);
  attn_kernel<<<grid, 512, 0, stream>>>(q, allowed, Kb, VT, out);
}